// Round 2
// baseline (618.486 us; speedup 1.0000x reference)
//
#include <hip/hip_runtime.h>
#include <hip/hip_bf16.h>

// out[b, n] = sum_k w[b,k] * archs[k,n] * (n % 257 != 0)   for n in [0, 65536)
// M=2048, K=32, N=65536. Write-bound: 512 MiB output.
//
// Tiling: each block owns N_CHUNK=1024 contiguous positions (256 thr x float4)
// and a B_CHUNK=128 batch slice. archs slice lives in registers (32 x 4 floats
// per thread), reused across 128 batches -> archs global traffic is 16x8 MiB,
// mostly L3 hits. Weights are block-uniform -> scalar loads.

typedef float vfloat4 __attribute__((ext_vector_type(4)));  // native vector: OK for nontemporal builtins

constexpr int K = 32;
constexpr int D = 256;
constexpr int N = D * D;        // 65536
constexpr int NPT = 4;          // positions per thread (one float4)
constexpr int THREADS = 256;
constexpr int N_CHUNK = THREADS * NPT;  // 1024
constexpr int B_CHUNK = 128;

__global__ __launch_bounds__(THREADS, 1)
void explainer_kernel(const float* __restrict__ w,
                      const float* __restrict__ archs,
                      float* __restrict__ out,
                      int B) {
    const int nbase = blockIdx.x * N_CHUNK + threadIdx.x * NPT;
    const int bbase = blockIdx.y * B_CHUNK;

    // Load archs slice into registers: a[k][j] = archs[k, nbase+j], diag zeroed.
    float a[K][NPT];
#pragma unroll
    for (int k = 0; k < K; ++k) {
        const vfloat4 v = *reinterpret_cast<const vfloat4*>(archs + (size_t)k * N + nbase);
        a[k][0] = v.x; a[k][1] = v.y; a[k][2] = v.z; a[k][3] = v.w;
    }
    // Diagonal mask: n = d*256 + e has d==e iff n % 257 == 0.
#pragma unroll
    for (int j = 0; j < NPT; ++j) {
        if (((nbase + j) % 257) == 0) {
#pragma unroll
            for (int k = 0; k < K; ++k) a[k][j] = 0.0f;
        }
    }

    const int bend = min(bbase + B_CHUNK, B);
    for (int b = bbase; b < bend; ++b) {
        const float* __restrict__ wb = w + (size_t)b * K;  // uniform -> s_load
        float acc0 = 0.f, acc1 = 0.f, acc2 = 0.f, acc3 = 0.f;
#pragma unroll
        for (int k = 0; k < K; ++k) {
            const float wk = wb[k];
            acc0 = fmaf(wk, a[k][0], acc0);
            acc1 = fmaf(wk, a[k][1], acc1);
            acc2 = fmaf(wk, a[k][2], acc2);
            acc3 = fmaf(wk, a[k][3], acc3);
        }
        vfloat4 o; o.x = acc0; o.y = acc1; o.z = acc2; o.w = acc3;
        __builtin_nontemporal_store(o, reinterpret_cast<vfloat4*>(out + (size_t)b * N + nbase));
    }
}

extern "C" void kernel_launch(void* const* d_in, const int* in_sizes, int n_in,
                              void* d_out, int out_size, void* d_ws, size_t ws_size,
                              hipStream_t stream) {
    const float* w     = (const float*)d_in[0];   // (B, 32)
    const float* archs = (const float*)d_in[1];   // (32, 256, 256)
    float* out = (float*)d_out;                   // (B, 256, 256)

    const int B = in_sizes[0] / K;                // 2048
    const int grid_x = N / N_CHUNK;               // 64
    const int grid_y = (B + B_CHUNK - 1) / B_CHUNK;  // 16

    dim3 grid(grid_x, grid_y);
    dim3 block(THREADS);
    explainer_kernel<<<grid, block, 0, stream>>>(w, archs, out, B);
}